// Round 1
// baseline (487.567 us; speedup 1.0000x reference)
//
#include <hip/hip_runtime.h>

// RandomShiftsAug: out[n,c,i,j] = x[n,c, clamp(i+sy-4,0,127), clamp(j+sx-4,0,127)]
// (bilinear grid_sample degenerates to integer shift since shifts are integers
// and the grid is built on pixel centers of the padded image).

#define NN  512
#define CC  9
#define HH  128
#define PADV 4

__global__ __launch_bounds__(256) void shift_copy_kernel(
    const float* __restrict__ x,
    const int*   __restrict__ shift,
    float*       __restrict__ out)
{
    // One thread = 4 consecutive output columns (float4 store).
    // tid layout: (((n*CC + c)*HH + i)*32 + jt), j = jt*4
    int tid = blockIdx.x * blockDim.x + threadIdx.x;
    int jt   = tid & 31;          // 128/4 = 32 vectors per row
    int rest = tid >> 5;
    int i    = rest & (HH - 1);
    rest >>= 7;
    int c    = rest % CC;
    int n    = rest / CC;
    if (n >= NN) return;

    int sx = shift[2 * n + 0] - PADV;   // column (x) shift, in [-4, 4]
    int sy = shift[2 * n + 1] - PADV;   // row    (y) shift, in [-4, 4]

    int ry = i + sy;
    ry = ry < 0 ? 0 : (ry > HH - 1 ? HH - 1 : ry);

    const float* __restrict__ xrow =
        x + ((size_t)(n * CC + c) * HH + ry) * HH;

    int j0 = jt * 4 + sx;
    float4 v;
    {
        int r;
        r = j0 + 0; r = r < 0 ? 0 : (r > HH - 1 ? HH - 1 : r); v.x = xrow[r];
        r = j0 + 1; r = r < 0 ? 0 : (r > HH - 1 ? HH - 1 : r); v.y = xrow[r];
        r = j0 + 2; r = r < 0 ? 0 : (r > HH - 1 ? HH - 1 : r); v.z = xrow[r];
        r = j0 + 3; r = r < 0 ? 0 : (r > HH - 1 ? HH - 1 : r); v.w = xrow[r];
    }

    float4* outp = (float4*)(out + ((size_t)(n * CC + c) * HH + i) * HH + jt * 4);
    *outp = v;
}

extern "C" void kernel_launch(void* const* d_in, const int* in_sizes, int n_in,
                              void* d_out, int out_size, void* d_ws, size_t ws_size,
                              hipStream_t stream)
{
    const float* x     = (const float*)d_in[0];
    const int*   shift = (const int*)d_in[1];
    float*       out   = (float*)d_out;

    // total threads = N*C*H*(H/4) = 512*9*128*32 = 18,874,368
    const int total_threads = NN * CC * HH * (HH / 4);
    const int block = 256;
    const int grid  = (total_threads + block - 1) / block;   // 73728

    shift_copy_kernel<<<grid, block, 0, stream>>>(x, shift, out);
}